// Round 4
// baseline (8189.731 us; speedup 1.0000x reference)
//
#include <hip/hip_runtime.h>

#define DDIM 2048
#define BDIM 512
#define NELEM (BDIM * DDIM)
#define NV4 (NELEM / 4)
#define NW4 (DDIM * DDIM / 4)

#define SC_DT 0
#define SC_DONE 1
#define SC_ERR 2
#define SC_SP 3

#define TOLF 0.01f
#define MIN_DTF 0.1f
#define SPEED_TOLF 1e-3f

typedef _Float16 half8 __attribute__((ext_vector_type(8)));
typedef _Float16 half4v __attribute__((ext_vector_type(4)));
typedef float f32x4 __attribute__((ext_vector_type(4)));

__device__ __forceinline__ void glds16(const _Float16* g, _Float16* l) {
    __builtin_amdgcn_global_load_lds((__attribute__((address_space(1))) void*)g,
                                     (__attribute__((address_space(3))) void*)l, 16, 0, 0);
}

__device__ __forceinline__ void split_f16(float y, _Float16& h, _Float16& l) {
    h = (_Float16)y;
    l = (_Float16)(y - (float)h);
}

__device__ __forceinline__ float reflect_f(float v) {
    int i = (int)v;
    return ((i & 1) == 0) ? v : 1.0f - v;
}

// ---------------- init / conversion kernels ----------------

__global__ void wconv_kernel(const float* __restrict__ W, _Float16* __restrict__ Wh,
                             _Float16* __restrict__ Wl) {
    int tid = blockIdx.x * blockDim.x + threadIdx.x;
    const float4* Wv = (const float4*)W;
    for (int i = tid; i < NW4; i += gridDim.x * blockDim.x) {
        float4 v = Wv[i];
        half4v h, l;
        float vv[4] = {v.x, v.y, v.z, v.w};
#pragma unroll
        for (int q = 0; q < 4; ++q) {
            _Float16 hh, ll;
            split_f16(vv[q], hh, ll);
            h[q] = hh;
            l[q] = ll;
        }
        *(half4v*)&Wh[(size_t)i * 4] = h;
        *(half4v*)&Wl[(size_t)i * 4] = l;
    }
}

__global__ void init_kernel(const float* __restrict__ x0, float* __restrict__ x,
                            _Float16* __restrict__ Axh, _Float16* __restrict__ Axl,
                            float* __restrict__ scal) {
    int tid = blockIdx.x * blockDim.x + threadIdx.x;
    const float4* X0 = (const float4*)x0;
    float4* X = (float4*)x;
    for (int i = tid; i < NV4; i += gridDim.x * blockDim.x) {
        float4 v = X0[i];
        X[i] = v;
        half4v h, l;
        float vv[4] = {v.x, v.y, v.z, v.w};
#pragma unroll
        for (int q = 0; q < 4; ++q) {
            float y = reflect_f(vv[q]);
            _Float16 hh, ll;
            split_f16(y, hh, ll);
            h[q] = hh;
            l[q] = ll;
        }
        *(half4v*)&Axh[(size_t)i * 4] = h;
        *(half4v*)&Axl[(size_t)i * 4] = l;
    }
    if (tid == 0) {
        scal[SC_DT] = 0.1f;
        ((unsigned int*)scal)[SC_DONE] = 0u;
        scal[SC_ERR] = 0.0f;
        scal[SC_SP] = 0.0f;
        scal[8 + SC_ERR] = 0.0f;
        scal[8 + SC_SP] = 0.0f;
    }
}

// ---------------- fused stage GEMM (K-split, 8 waves, lo-from-global) ----------------
// kS = sign(xs_S) * (G(xs_S) @ W + bias), 3-pass split-f16 MFMA.
// Hi matrices (Ah, Wh) staged via global_load_lds; lo matrices (Al, Wl) are
// loaded straight into register fragments from global (L1/L2), halving LDS
// traffic. Waves 0-3 integrate k in [0,1024), waves 4-7 [1024,2048); partials
// exchanged through LDS at the end.

template <int S>
__global__ __launch_bounds__(512, 2) void stage_kernel(
    const _Float16* __restrict__ Ah, const _Float16* __restrict__ Al,
    _Float16* __restrict__ Aoh, _Float16* __restrict__ Aol, const _Float16* __restrict__ Wh,
    const _Float16* __restrict__ Wl, const float* __restrict__ bias,
    const float* __restrict__ xg, const float* __restrict__ gk1, const float* __restrict__ gk2,
    const float* __restrict__ gk3, const float* __restrict__ gk4, const float* __restrict__ gk5,
    float* __restrict__ kout, float* __restrict__ x5out, float* __restrict__ scal) {
    __shared__ __align__(16) _Float16 lds[2][2][2][64 * 64];  // [kgroup][buf][Ah,Wh][...]
    __shared__ float serr[8], ssp[8];

    const int tid = threadIdx.x;
    const int li = tid & 63;
    const int wid = tid >> 6;  // 0..7
    const int g = wid >> 2;    // k-split group
    const int w4 = wid & 3;    // wave-in-group
    const int wm = w4 >> 1, wn = w4 & 1;

    // XCD-aware swizzle: 256 blocks = 8 XCDs x 32; each XCD = 4(m) x 8(n) super-tile
    const int bid = blockIdx.x;
    const int xcd = bid & 7, jj = bid >> 3;
    const int bm = (xcd & 1) * 4 + (jj & 3);
    const int bn = (xcd >> 1) * 8 + (jj >> 2);

    const int kbase = g * 1024;

    f32x4 acc[2][2];
#pragma unroll
    for (int a = 0; a < 2; ++a)
#pragma unroll
        for (int b = 0; b < 2; ++b) acc[a][b] = (f32x4)(0.0f);

    // lo-fragment global base pointers (fragment layout == 16B/lane contiguous)
    const _Float16* Al_base =
        Al + (size_t)(bm * 64 + wm * 32 + (li & 15)) * DDIM + kbase + ((li >> 4) << 3);
    const _Float16* Wl_base =
        Wl + (size_t)(bn * 64 + wn * 32 + (li & 15)) * DDIM + kbase + ((li >> 4) << 3);

    // hi staging: Ah/Wh tiles, 8KB each, by this group's 4 waves (4 glds/thread)
    auto stage_hi = [&](int buf, int k0) {
#pragma unroll
        for (int cc = 0; cc < 2; ++cc) {
            int c = w4 + cc * 4;
            int row = c * 8 + (li >> 3);
            int clog = (li & 7) ^ (row & 7);  // XOR chunk swizzle (involution)
            int ga = (bm * 64 + row) * DDIM + k0 + clog * 8;
            int gw = (bn * 64 + row) * DDIM + k0 + clog * 8;
            int lo_ = c * 512 + li * 8;
            glds16(Ah + ga, &lds[g][buf][0][lo_]);
            glds16(Wh + gw, &lds[g][buf][1][lo_]);
        }
    };

    // lo fragments: [0..3] = Al[ks][mi], [4..7] = Wl[ks][ni]  (8 b128 loads)
    auto load_lo = [&](half8(&lo)[8], int t) {
#pragma unroll
        for (int ks = 0; ks < 2; ++ks) {
#pragma unroll
            for (int mi = 0; mi < 2; ++mi)
                lo[ks * 2 + mi] = *(const half8*)(Al_base + (size_t)mi * 16 * DDIM + t * 64 + ks * 32);
#pragma unroll
            for (int ni = 0; ni < 2; ++ni)
                lo[4 + ks * 2 + ni] = *(const half8*)(Wl_base + (size_t)ni * 16 * DDIM + t * 64 + ks * 32);
        }
    };

    auto rdfrag = [&](int buf, int mat, int rbase, int ks) -> half8 {
        int r = rbase + (li & 15);
        int cl = ks * 4 + (li >> 4);
        int off = r * 64 + ((cl ^ (r & 7)) << 3);
        return *(const half8*)&lds[g][buf][mat][off];
    };

    auto compute = [&](int buf, half8(&lo)[8]) {
#pragma unroll
        for (int ks = 0; ks < 2; ++ks) {
            half8 ah[2], bh[2];
#pragma unroll
            for (int f = 0; f < 2; ++f) {
                ah[f] = rdfrag(buf, 0, wm * 32 + f * 16, ks);
                bh[f] = rdfrag(buf, 1, wn * 32 + f * 16, ks);
            }
            __builtin_amdgcn_s_setprio(1);
#pragma unroll
            for (int mi = 0; mi < 2; ++mi)
#pragma unroll
                for (int ni = 0; ni < 2; ++ni) {
                    acc[mi][ni] = __builtin_amdgcn_mfma_f32_16x16x32_f16(ah[mi], bh[ni],
                                                                         acc[mi][ni], 0, 0, 0);
                    acc[mi][ni] = __builtin_amdgcn_mfma_f32_16x16x32_f16(
                        ah[mi], lo[4 + ks * 2 + ni], acc[mi][ni], 0, 0, 0);
                    acc[mi][ni] = __builtin_amdgcn_mfma_f32_16x16x32_f16(
                        lo[ks * 2 + mi], bh[ni], acc[mi][ni], 0, 0, 0);
                }
            __builtin_amdgcn_s_setprio(0);
        }
    };

    // --- pipelined K loop: 16 k-tiles of BK=64 per group, counted vmcnt ---
    half8 loA[8], loB[8];
    stage_hi(0, kbase);
    load_lo(loA, 0);
#pragma unroll 1
    for (int tt = 0; tt < 8; ++tt) {
        const int t0 = tt * 2;
        // even tile t0: compute(buf0, loA); prefetch t0+1 -> buf1/loB
        stage_hi(1, kbase + (t0 + 1) * 64);
        load_lo(loB, t0 + 1);
        asm volatile("s_waitcnt vmcnt(12)" ::: "memory");
        __builtin_amdgcn_sched_barrier(0);
        __builtin_amdgcn_s_barrier();
        compute(0, loA);
        __builtin_amdgcn_s_barrier();
        // odd tile t0+1: compute(buf1, loB); prefetch t0+2 -> buf0/loA
        if (tt < 7) {
            stage_hi(0, kbase + (t0 + 2) * 64);
            load_lo(loA, t0 + 2);
            asm volatile("s_waitcnt vmcnt(12)" ::: "memory");
        } else {
            asm volatile("s_waitcnt vmcnt(0)" ::: "memory");
        }
        __builtin_amdgcn_sched_barrier(0);
        __builtin_amdgcn_s_barrier();
        compute(1, loB);
        __builtin_amdgcn_s_barrier();
    }

    // --- partial-sum exchange: group g keeps the mi==g band, ships the other ---
    float4* xch = (float4*)&lds[0][0][0][0];
#pragma unroll
    for (int ni = 0; ni < 2; ++ni) {
        int slot = ((g * 4 + w4) * 2 + ni) * 64 + li;
        if (g == 0)
            xch[slot] = make_float4(acc[1][ni][0], acc[1][ni][1], acc[1][ni][2], acc[1][ni][3]);
        else
            xch[slot] = make_float4(acc[0][ni][0], acc[0][ni][1], acc[0][ni][2], acc[0][ni][3]);
    }
    __syncthreads();
    f32x4 fin[2];
#pragma unroll
    for (int ni = 0; ni < 2; ++ni) {
        int slot = (((1 - g) * 4 + w4) * 2 + ni) * 64 + li;
        float4 p = xch[slot];
        f32x4 mine = (g == 0) ? acc[0][ni] : acc[1][ni];
        mine[0] += p.x;
        mine[1] += p.y;
        mine[2] += p.z;
        mine[3] += p.w;
        fin[ni] = mine;
    }

    // --- fused epilogue: each thread finalizes 8 elems (rows wm*32+g*16+..) ---
    const float dt = scal[SC_DT];
    const int lrow = li >> 4, lcol = li & 15;
    const float bias0 = bias[bn * 64 + wn * 32 + lcol];
    const float bias1 = bias[bn * 64 + wn * 32 + 16 + lcol];
    float lerr = 0.0f, lsp = 0.0f;

#pragma unroll
    for (int r = 0; r < 4; ++r) {
        int m = bm * 64 + wm * 32 + g * 16 + lrow * 4 + r;
        size_t base = (size_t)m * DDIM;
#pragma unroll
        for (int ni = 0; ni < 2; ++ni) {
            int n = bn * 64 + wn * 32 + ni * 16 + lcol;
            size_t idx = base + n;
            float accv = fin[ni][r] + (ni == 0 ? bias0 : bias1);
            float xv = xg[idx];
            float lk1 = 0.f, lk2 = 0.f, lk3 = 0.f, lk4 = 0.f, lk5 = 0.f;
            if constexpr (S >= 2) lk1 = gk1[idx];
            if constexpr (S >= 3) lk2 = gk2[idx];
            if constexpr (S >= 4) lk3 = gk3[idx];
            if constexpr (S >= 5) lk4 = gk4[idx];
            if constexpr (S >= 6) lk5 = gk5[idx];
            float xs;
            if constexpr (S == 1) xs = xv;
            if constexpr (S == 2) xs = xv + dt * (0.25f * lk1);
            if constexpr (S == 3)
                xs = xv + dt * ((float)(3.0 / 32.0) * lk1 + (float)(9.0 / 32.0) * lk2);
            if constexpr (S == 4)
                xs = xv + dt * ((float)(1932.0 / 2197.0) * lk1 + (float)(-7200.0 / 2197.0) * lk2 +
                                (float)(7296.0 / 2197.0) * lk3);
            if constexpr (S == 5)
                xs = xv + dt * ((float)(439.0 / 216.0) * lk1 - 8.0f * lk2 +
                                (float)(3680.0 / 513.0) * lk3 + (float)(-845.0 / 4104.0) * lk4);
            if constexpr (S == 6)
                xs = xv + dt * ((float)(-8.0 / 27.0) * lk1 + 2.0f * lk2 +
                                (float)(-3544.0 / 2565.0) * lk3 + (float)(1859.0 / 4104.0) * lk4 +
                                (float)(-11.0 / 40.0) * lk5);
            float sgn = (((int)xs) & 1) ? -1.0f : 1.0f;
            float kv = sgn * accv;
            if constexpr (S < 6) {
                kout[idx] = kv;
                float xn;
                if constexpr (S == 1) xn = xv + dt * (0.25f * kv);
                if constexpr (S == 2)
                    xn = xv + dt * ((float)(3.0 / 32.0) * lk1 + (float)(9.0 / 32.0) * kv);
                if constexpr (S == 3)
                    xn = xv + dt * ((float)(1932.0 / 2197.0) * lk1 +
                                    (float)(-7200.0 / 2197.0) * lk2 + (float)(7296.0 / 2197.0) * kv);
                if constexpr (S == 4)
                    xn = xv + dt * ((float)(439.0 / 216.0) * lk1 - 8.0f * lk2 +
                                    (float)(3680.0 / 513.0) * lk3 + (float)(-845.0 / 4104.0) * kv);
                if constexpr (S == 5)
                    xn = xv + dt * ((float)(-8.0 / 27.0) * lk1 + 2.0f * lk2 +
                                    (float)(-3544.0 / 2565.0) * lk3 +
                                    (float)(1859.0 / 4104.0) * lk4 + (float)(-11.0 / 40.0) * kv);
                float y = reflect_f(xn);
                _Float16 hh, ll;
                split_f16(y, hh, ll);
                Aoh[idx] = hh;
                Aol[idx] = ll;
            } else {
                float x5 = xv + dt * ((float)(16.0 / 135.0) * lk1 + (float)(6656.0 / 12825.0) * lk3 +
                                      (float)(28561.0 / 56430.0) * lk4 + (float)(-9.0 / 50.0) * lk5 +
                                      (float)(2.0 / 55.0) * kv);
                float x4 = xv + dt * ((float)(25.0 / 216.0) * lk1 + (float)(1408.0 / 2565.0) * lk3 +
                                      (float)(2197.0 / 4104.0) * lk4 + (float)(-1.0 / 5.0) * lk5);
                lerr = fmaxf(lerr, fabsf(x5 - x4));
                lsp = fmaxf(lsp, fabsf(x5 - xv));
                x5out[idx] = x5;
            }
        }
    }

    if constexpr (S == 6) {
#pragma unroll
        for (int off = 32; off > 0; off >>= 1) {
            lerr = fmaxf(lerr, __shfl_down(lerr, off));
            lsp = fmaxf(lsp, __shfl_down(lsp, off));
        }
        if (li == 0) {
            serr[wid] = lerr;
            ssp[wid] = lsp;
        }
        __syncthreads();
        if (tid == 0) {
            float e = serr[0], s = ssp[0];
#pragma unroll
            for (int w = 1; w < 8; ++w) {
                e = fmaxf(e, serr[w]);
                s = fmaxf(s, ssp[w]);
            }
            atomicMax((unsigned int*)&scal[SC_ERR], __float_as_uint(e));
            atomicMax((unsigned int*)&scal[SC_SP], __float_as_uint(s));
        }
    }
}

// ---------------- fused scalar update + commit ----------------
// Every block recomputes the (deterministic) accept decision locally from the
// read-parity scalar slots; block 0 writes the next-parity slots. On rejected
// steps all x/A traffic is skipped (x and Ax remain valid).

__global__ void commit_fused(float* __restrict__ x, const float* __restrict__ x5,
                             _Float16* __restrict__ Axh, _Float16* __restrict__ Axl,
                             const float* __restrict__ scal_rd, float* __restrict__ scal_wr) {
    float dt = scal_rd[SC_DT];
    float err = scal_rd[SC_ERR];
    float sp = scal_rd[SC_SP];
    unsigned int done = ((const unsigned int*)scal_rd)[SC_DONE];
    bool accept = err < TOLF;
    bool step = accept && (done == 0u);
    float speed = sp / dt;
    unsigned int done_new = (done || (step && speed < SPEED_TOLF)) ? 1u : 0u;
    float scale = 0.9f * powf(TOLF / (err + 1e-12f), 0.2f);
    scale = fminf(fmaxf(scale, 0.1f), 4.0f);
    float dtn = fmaxf(dt * scale, MIN_DTF);
    if (blockIdx.x == 0 && threadIdx.x == 0) {
        scal_wr[SC_DT] = done ? dt : dtn;
        ((unsigned int*)scal_wr)[SC_DONE] = done_new;
        scal_wr[SC_ERR] = 0.0f;
        scal_wr[SC_SP] = 0.0f;
    }
    if (!step) return;  // x unchanged; Ax split still valid
    int tid = blockIdx.x * blockDim.x + threadIdx.x;
    float4* X = (float4*)x;
    const float4* X5 = (const float4*)x5;
    for (int i = tid; i < NV4; i += gridDim.x * blockDim.x) {
        float4 v = X5[i];
        X[i] = v;
        half4v h, l;
        float vv[4] = {v.x, v.y, v.z, v.w};
#pragma unroll
        for (int q = 0; q < 4; ++q) {
            float y = reflect_f(vv[q]);
            _Float16 hh, ll;
            split_f16(y, hh, ll);
            h[q] = hh;
            l[q] = ll;
        }
        *(half4v*)&Axh[(size_t)i * 4] = h;
        *(half4v*)&Axl[(size_t)i * 4] = l;
    }
}

// ---------------- launch ----------------

extern "C" void kernel_launch(void* const* d_in, const int* in_sizes, int n_in, void* d_out,
                              int out_size, void* d_ws, size_t ws_size, hipStream_t stream) {
    const float* x0 = (const float*)d_in[0];
    const float* W = (const float*)d_in[1];
    const float* bias = (const float*)d_in[2];
    float* x = (float*)d_out;

    float* ws = (float*)d_ws;
    float* k1 = ws + 0 * (size_t)NELEM;
    float* k2 = ws + 1 * (size_t)NELEM;
    float* k3 = ws + 2 * (size_t)NELEM;
    float* k4 = ws + 3 * (size_t)NELEM;
    float* k5 = ws + 4 * (size_t)NELEM;
    float* x5 = ws + 5 * (size_t)NELEM;
    float* scal = ws + 6 * (size_t)NELEM;  // 2 parity slots x 8 floats
    _Float16* hb = (_Float16*)(ws + 6 * (size_t)NELEM + 64);
    _Float16* Axh = hb + 0 * (size_t)NELEM;
    _Float16* Axl = hb + 1 * (size_t)NELEM;
    _Float16* P0h = hb + 2 * (size_t)NELEM;
    _Float16* P0l = hb + 3 * (size_t)NELEM;
    _Float16* P1h = hb + 4 * (size_t)NELEM;
    _Float16* P1l = hb + 5 * (size_t)NELEM;
    _Float16* Wh = hb + 6 * (size_t)NELEM;
    _Float16* Wl = Wh + (size_t)DDIM * DDIM;

    wconv_kernel<<<2048, 256, 0, stream>>>(W, Wh, Wl);
    init_kernel<<<1024, 256, 0, stream>>>(x0, x, Axh, Axl, scal);

    for (int it = 0; it < 32; ++it) {
        float* sp = scal + (it & 1) * 8;
        float* sn = scal + ((it + 1) & 1) * 8;
        stage_kernel<1><<<256, 512, 0, stream>>>(Axh, Axl, P0h, P0l, Wh, Wl, bias, x, k1, k2, k3,
                                                 k4, k5, k1, x5, sp);
        stage_kernel<2><<<256, 512, 0, stream>>>(P0h, P0l, P1h, P1l, Wh, Wl, bias, x, k1, k2, k3,
                                                 k4, k5, k2, x5, sp);
        stage_kernel<3><<<256, 512, 0, stream>>>(P1h, P1l, P0h, P0l, Wh, Wl, bias, x, k1, k2, k3,
                                                 k4, k5, k3, x5, sp);
        stage_kernel<4><<<256, 512, 0, stream>>>(P0h, P0l, P1h, P1l, Wh, Wl, bias, x, k1, k2, k3,
                                                 k4, k5, k4, x5, sp);
        stage_kernel<5><<<256, 512, 0, stream>>>(P1h, P1l, P0h, P0l, Wh, Wl, bias, x, k1, k2, k3,
                                                 k4, k5, k5, x5, sp);
        stage_kernel<6><<<256, 512, 0, stream>>>(P0h, P0l, P1h, P1l, Wh, Wl, bias, x, k1, k2, k3,
                                                 k4, k5, k1, x5, sp);
        commit_fused<<<1024, 256, 0, stream>>>(x, x5, Axh, Axl, sp, sn);
    }
}

// Round 5
// 4986.287 us; speedup vs baseline: 1.6425x; 1.6425x over previous
//
#include <hip/hip_runtime.h>

#define DDIM 2048
#define BDIM 512
#define NELEM (BDIM * DDIM)
#define NV4 (NELEM / 4)
#define NW4 (DDIM * DDIM / 4)

#define SC_DT 0
#define SC_DONE 1
#define SC_ERR 2
#define SC_SP 3

#define TOLF 0.01f
#define MIN_DTF 0.1f
#define SPEED_TOLF 1e-3f

typedef _Float16 half8 __attribute__((ext_vector_type(8)));
typedef _Float16 half4v __attribute__((ext_vector_type(4)));
typedef float f32x4 __attribute__((ext_vector_type(4)));

__device__ __forceinline__ void glds16(const _Float16* g, _Float16* l) {
    __builtin_amdgcn_global_load_lds((__attribute__((address_space(1))) void*)g,
                                     (__attribute__((address_space(3))) void*)l, 16, 0, 0);
}

__device__ __forceinline__ void split_f16(float y, _Float16& h, _Float16& l) {
    h = (_Float16)y;
    l = (_Float16)(y - (float)h);
}

__device__ __forceinline__ float reflect_f(float v) {
    int i = (int)v;
    return ((i & 1) == 0) ? v : 1.0f - v;
}

// ---------------- init / conversion kernels ----------------

// W -> fragment-major Whf/Wlf.  Fragment (n16, k32): 64 lanes x 8 halfs, so that
// a wave's 16B/lane MFMA B-operand load is one contiguous 1KB chunk.
// Element W[r][c]: n16=r>>4, lane=(c&31)>>3 * 16 + (r&15), k32=c>>5, j=c&7.
// idx = ((n16*64 + k32)*64 + lane)*8 + j.
__global__ void wconv_kernel(const float* __restrict__ W, _Float16* __restrict__ Whf,
                             _Float16* __restrict__ Wlf) {
    int tid = blockIdx.x * blockDim.x + threadIdx.x;
    const float4* Wv = (const float4*)W;
    for (int i = tid; i < NW4; i += gridDim.x * blockDim.x) {
        float4 v = Wv[i];
        int r = (i * 4) >> 11;        // /DDIM
        int c0 = (i * 4) & 2047;      // %DDIM
        int n16 = r >> 4;
        int lane = (((c0 & 31) >> 3) << 4) + (r & 15);
        int k32 = c0 >> 5;
        int j0 = c0 & 7;  // 0 or 4
        size_t idx = (((size_t)n16 * 64 + k32) * 64 + lane) * 8 + j0;
        half4v h, l;
        float vv[4] = {v.x, v.y, v.z, v.w};
#pragma unroll
        for (int q = 0; q < 4; ++q) {
            _Float16 hh, ll;
            split_f16(vv[q], hh, ll);
            h[q] = hh;
            l[q] = ll;
        }
        *(half4v*)&Whf[idx] = h;
        *(half4v*)&Wlf[idx] = l;
    }
}

__global__ void init_kernel(const float* __restrict__ x0, float* __restrict__ x,
                            _Float16* __restrict__ Axh, _Float16* __restrict__ Axl,
                            float* __restrict__ scal) {
    int tid = blockIdx.x * blockDim.x + threadIdx.x;
    const float4* X0 = (const float4*)x0;
    float4* X = (float4*)x;
    for (int i = tid; i < NV4; i += gridDim.x * blockDim.x) {
        float4 v = X0[i];
        X[i] = v;
        half4v h, l;
        float vv[4] = {v.x, v.y, v.z, v.w};
#pragma unroll
        for (int q = 0; q < 4; ++q) {
            float y = reflect_f(vv[q]);
            _Float16 hh, ll;
            split_f16(y, hh, ll);
            h[q] = hh;
            l[q] = ll;
        }
        *(half4v*)&Axh[(size_t)i * 4] = h;
        *(half4v*)&Axl[(size_t)i * 4] = l;
    }
    if (tid == 0) {
        scal[SC_DT] = 0.1f;
        ((unsigned int*)scal)[SC_DONE] = 0u;
        scal[SC_ERR] = 0.0f;
        scal[SC_SP] = 0.0f;
        scal[8 + SC_ERR] = 0.0f;
        scal[8 + SC_SP] = 0.0f;
    }
}

// ---------------- fused stage GEMM ----------------
// kS = sign(xs_S) * (G(xs_S) @ W + bias), 3-pass split-f16 MFMA.
// A (hi+lo) staged in LDS via global_load_lds; W (hi+lo) loaded from the
// constant fragment-major buffers straight into NAMED registers (contiguous
// 1KB/wave loads, one tile ahead). Waves 0-3: k in [0,1024), 4-7: [1024,2048).

#define MFMA_AC(a, b, c) c = __builtin_amdgcn_mfma_f32_16x16x32_f16(a, b, c, 0, 0, 0)

#define LOADWF(P, t)                                                      \
    P##h00 = *(const half8*)(wbH0 + (g * 32 + (t) * 2) * 512);            \
    P##h10 = *(const half8*)(wbH1 + (g * 32 + (t) * 2) * 512);            \
    P##h01 = *(const half8*)(wbH0 + (g * 32 + (t) * 2 + 1) * 512);        \
    P##h11 = *(const half8*)(wbH1 + (g * 32 + (t) * 2 + 1) * 512);        \
    P##l00 = *(const half8*)(wbL0 + (g * 32 + (t) * 2) * 512);            \
    P##l10 = *(const half8*)(wbL1 + (g * 32 + (t) * 2) * 512);            \
    P##l01 = *(const half8*)(wbL0 + (g * 32 + (t) * 2 + 1) * 512);        \
    P##l11 = *(const half8*)(wbL1 + (g * 32 + (t) * 2 + 1) * 512);

#define COMPUTE(buf, P)                                                   \
    {                                                                     \
        half8 a0 = rdfrag(buf, 0, wm * 32, 0);                            \
        half8 a1 = rdfrag(buf, 0, wm * 32 + 16, 0);                       \
        half8 l0 = rdfrag(buf, 1, wm * 32, 0);                            \
        half8 l1 = rdfrag(buf, 1, wm * 32 + 16, 0);                       \
        __builtin_amdgcn_s_setprio(1);                                    \
        MFMA_AC(a0, P##h00, acc00);                                       \
        MFMA_AC(a0, P##h10, acc01);                                       \
        MFMA_AC(a1, P##h00, acc10);                                       \
        MFMA_AC(a1, P##h10, acc11);                                       \
        MFMA_AC(a0, P##l00, acc00);                                       \
        MFMA_AC(a0, P##l10, acc01);                                       \
        MFMA_AC(a1, P##l00, acc10);                                       \
        MFMA_AC(a1, P##l10, acc11);                                       \
        MFMA_AC(l0, P##h00, acc00);                                       \
        MFMA_AC(l0, P##h10, acc01);                                       \
        MFMA_AC(l1, P##h00, acc10);                                       \
        MFMA_AC(l1, P##h10, acc11);                                       \
        __builtin_amdgcn_s_setprio(0);                                    \
        a0 = rdfrag(buf, 0, wm * 32, 1);                                  \
        a1 = rdfrag(buf, 0, wm * 32 + 16, 1);                             \
        l0 = rdfrag(buf, 1, wm * 32, 1);                                  \
        l1 = rdfrag(buf, 1, wm * 32 + 16, 1);                             \
        __builtin_amdgcn_s_setprio(1);                                    \
        MFMA_AC(a0, P##h01, acc00);                                       \
        MFMA_AC(a0, P##h11, acc01);                                       \
        MFMA_AC(a1, P##h01, acc10);                                       \
        MFMA_AC(a1, P##h11, acc11);                                       \
        MFMA_AC(a0, P##l01, acc00);                                       \
        MFMA_AC(a0, P##l11, acc01);                                       \
        MFMA_AC(a1, P##l01, acc10);                                       \
        MFMA_AC(a1, P##l11, acc11);                                       \
        MFMA_AC(l0, P##h01, acc00);                                       \
        MFMA_AC(l0, P##h11, acc01);                                       \
        MFMA_AC(l1, P##h01, acc10);                                       \
        MFMA_AC(l1, P##h11, acc11);                                       \
        __builtin_amdgcn_s_setprio(0);                                    \
    }

template <int S>
__global__ __launch_bounds__(512, 2) void stage_kernel(
    const _Float16* __restrict__ Ah, const _Float16* __restrict__ Al,
    _Float16* __restrict__ Aoh, _Float16* __restrict__ Aol, const _Float16* __restrict__ Whf,
    const _Float16* __restrict__ Wlf, const float* __restrict__ bias,
    const float* __restrict__ xg, const float* __restrict__ gk1, const float* __restrict__ gk2,
    const float* __restrict__ gk3, const float* __restrict__ gk4, const float* __restrict__ gk5,
    float* __restrict__ kout, float* __restrict__ x5out, float* __restrict__ scal) {
    __shared__ __align__(16) _Float16 lds[2][2][2][64 * 64];  // [kgroup][buf][Ah,Al][...]
    __shared__ float serr[8], ssp[8];

    const int tid = threadIdx.x;
    const int li = tid & 63;
    const int wid = tid >> 6;  // 0..7
    const int g = wid >> 2;    // k-split group
    const int w4 = wid & 3;    // wave-in-group
    const int wm = w4 >> 1, wn = w4 & 1;

    // XCD-aware swizzle: 256 blocks = 8 XCDs x 32; each XCD = 4(m) x 8(n) super-tile
    const int bid = blockIdx.x;
    const int xcd = bid & 7, jj = bid >> 3;
    const int bm = (xcd & 1) * 4 + (jj & 3);
    const int bn = (xcd >> 1) * 8 + (jj >> 2);

    const int kbase = g * 1024;

    f32x4 acc00 = (f32x4)(0.0f), acc01 = (f32x4)(0.0f);
    f32x4 acc10 = (f32x4)(0.0f), acc11 = (f32x4)(0.0f);

    // W fragment-major bases for this wave's two 16-col blocks
    const int n16a = bn * 4 + wn * 2, n16b = n16a + 1;
    const _Float16* wbH0 = Whf + (size_t)n16a * 32768 + li * 8;
    const _Float16* wbH1 = Whf + (size_t)n16b * 32768 + li * 8;
    const _Float16* wbL0 = Wlf + (size_t)n16a * 32768 + li * 8;
    const _Float16* wbL1 = Wlf + (size_t)n16b * 32768 + li * 8;

    // A staging: Ah/Al tiles, 8KB each per group tile (4 glds/thread)
    auto stage_A = [&](int buf, int k0) {
#pragma unroll
        for (int cc = 0; cc < 2; ++cc) {
            int c = w4 + cc * 4;
            int row = c * 8 + (li >> 3);
            int clog = (li & 7) ^ (row & 7);  // XOR chunk swizzle (involution)
            int ga = (bm * 64 + row) * DDIM + k0 + clog * 8;
            int lo_ = c * 512 + li * 8;
            glds16(Ah + ga, &lds[g][buf][0][lo_]);
            glds16(Al + ga, &lds[g][buf][1][lo_]);
        }
    };

    auto rdfrag = [&](int buf, int mat, int rbase, int ks) -> half8 {
        int r = rbase + (li & 15);
        int cl = ks * 4 + (li >> 4);
        int off = r * 64 + ((cl ^ (r & 7)) << 3);
        return *(const half8*)&lds[g][buf][mat][off];
    };

    half8 Ph00, Ph10, Ph01, Ph11, Pl00, Pl10, Pl01, Pl11;
    half8 Qh00, Qh10, Qh01, Qh11, Ql00, Ql10, Ql01, Ql11;

    // --- pipelined K loop: 16 k-tiles of BK=64 per group, counted vmcnt ---
    stage_A(0, kbase);
    LOADWF(P, 0)
#pragma unroll 1
    for (int tt = 0; tt < 8; ++tt) {
        const int t0 = tt * 2;
        stage_A(1, kbase + (t0 + 1) * 64);
        LOADWF(Q, t0 + 1)
        asm volatile("s_waitcnt vmcnt(12)" ::: "memory");
        __builtin_amdgcn_sched_barrier(0);
        __builtin_amdgcn_s_barrier();
        COMPUTE(0, P)
        __builtin_amdgcn_s_barrier();
        if (tt < 7) {
            stage_A(0, kbase + (t0 + 2) * 64);
            LOADWF(P, t0 + 2)
            asm volatile("s_waitcnt vmcnt(12)" ::: "memory");
        } else {
            asm volatile("s_waitcnt vmcnt(0)" ::: "memory");
        }
        __builtin_amdgcn_sched_barrier(0);
        __builtin_amdgcn_s_barrier();
        COMPUTE(1, Q)
        __builtin_amdgcn_s_barrier();
    }

    // --- partial-sum exchange: group g keeps the mi==g band, ships the other ---
    f32x4 ship0 = (g == 0) ? acc10 : acc00;
    f32x4 ship1 = (g == 0) ? acc11 : acc01;
    f32x4 keep0 = (g == 0) ? acc00 : acc10;
    f32x4 keep1 = (g == 0) ? acc01 : acc11;
    float4* xch = (float4*)&lds[0][0][0][0];
    {
        int slot0 = ((g * 4 + w4) * 2 + 0) * 64 + li;
        int slot1 = ((g * 4 + w4) * 2 + 1) * 64 + li;
        xch[slot0] = make_float4(ship0[0], ship0[1], ship0[2], ship0[3]);
        xch[slot1] = make_float4(ship1[0], ship1[1], ship1[2], ship1[3]);
    }
    __syncthreads();
    f32x4 fin[2];
    {
        int slot0 = (((1 - g) * 4 + w4) * 2 + 0) * 64 + li;
        int slot1 = (((1 - g) * 4 + w4) * 2 + 1) * 64 + li;
        float4 p0 = xch[slot0];
        float4 p1 = xch[slot1];
        keep0[0] += p0.x; keep0[1] += p0.y; keep0[2] += p0.z; keep0[3] += p0.w;
        keep1[0] += p1.x; keep1[1] += p1.y; keep1[2] += p1.z; keep1[3] += p1.w;
        fin[0] = keep0;
        fin[1] = keep1;
    }

    // --- fused epilogue: each thread finalizes 8 elems (rows wm*32+g*16+..) ---
    const float dt = scal[SC_DT];
    const int lrow = li >> 4, lcol = li & 15;
    const float bias0 = bias[bn * 64 + wn * 32 + lcol];
    const float bias1 = bias[bn * 64 + wn * 32 + 16 + lcol];
    float lerr = 0.0f, lsp = 0.0f;

#pragma unroll
    for (int r = 0; r < 4; ++r) {
        int m = bm * 64 + wm * 32 + g * 16 + lrow * 4 + r;
        size_t base = (size_t)m * DDIM;
#pragma unroll
        for (int ni = 0; ni < 2; ++ni) {
            int n = bn * 64 + wn * 32 + ni * 16 + lcol;
            size_t idx = base + n;
            float accv = fin[ni][r] + (ni == 0 ? bias0 : bias1);
            float xv = xg[idx];
            float lk1 = 0.f, lk2 = 0.f, lk3 = 0.f, lk4 = 0.f, lk5 = 0.f;
            if constexpr (S >= 2) lk1 = gk1[idx];
            if constexpr (S >= 3) lk2 = gk2[idx];
            if constexpr (S >= 4) lk3 = gk3[idx];
            if constexpr (S >= 5) lk4 = gk4[idx];
            if constexpr (S >= 6) lk5 = gk5[idx];
            float xs;
            if constexpr (S == 1) xs = xv;
            if constexpr (S == 2) xs = xv + dt * (0.25f * lk1);
            if constexpr (S == 3)
                xs = xv + dt * ((float)(3.0 / 32.0) * lk1 + (float)(9.0 / 32.0) * lk2);
            if constexpr (S == 4)
                xs = xv + dt * ((float)(1932.0 / 2197.0) * lk1 + (float)(-7200.0 / 2197.0) * lk2 +
                                (float)(7296.0 / 2197.0) * lk3);
            if constexpr (S == 5)
                xs = xv + dt * ((float)(439.0 / 216.0) * lk1 - 8.0f * lk2 +
                                (float)(3680.0 / 513.0) * lk3 + (float)(-845.0 / 4104.0) * lk4);
            if constexpr (S == 6)
                xs = xv + dt * ((float)(-8.0 / 27.0) * lk1 + 2.0f * lk2 +
                                (float)(-3544.0 / 2565.0) * lk3 + (float)(1859.0 / 4104.0) * lk4 +
                                (float)(-11.0 / 40.0) * lk5);
            float sgn = (((int)xs) & 1) ? -1.0f : 1.0f;
            float kv = sgn * accv;
            if constexpr (S < 6) {
                kout[idx] = kv;
                float xn;
                if constexpr (S == 1) xn = xv + dt * (0.25f * kv);
                if constexpr (S == 2)
                    xn = xv + dt * ((float)(3.0 / 32.0) * lk1 + (float)(9.0 / 32.0) * kv);
                if constexpr (S == 3)
                    xn = xv + dt * ((float)(1932.0 / 2197.0) * lk1 +
                                    (float)(-7200.0 / 2197.0) * lk2 + (float)(7296.0 / 2197.0) * kv);
                if constexpr (S == 4)
                    xn = xv + dt * ((float)(439.0 / 216.0) * lk1 - 8.0f * lk2 +
                                    (float)(3680.0 / 513.0) * lk3 + (float)(-845.0 / 4104.0) * kv);
                if constexpr (S == 5)
                    xn = xv + dt * ((float)(-8.0 / 27.0) * lk1 + 2.0f * lk2 +
                                    (float)(-3544.0 / 2565.0) * lk3 +
                                    (float)(1859.0 / 4104.0) * lk4 + (float)(-11.0 / 40.0) * kv);
                float y = reflect_f(xn);
                _Float16 hh, ll;
                split_f16(y, hh, ll);
                Aoh[idx] = hh;
                Aol[idx] = ll;
            } else {
                float x5 = xv + dt * ((float)(16.0 / 135.0) * lk1 + (float)(6656.0 / 12825.0) * lk3 +
                                      (float)(28561.0 / 56430.0) * lk4 + (float)(-9.0 / 50.0) * lk5 +
                                      (float)(2.0 / 55.0) * kv);
                float x4 = xv + dt * ((float)(25.0 / 216.0) * lk1 + (float)(1408.0 / 2565.0) * lk3 +
                                      (float)(2197.0 / 4104.0) * lk4 + (float)(-1.0 / 5.0) * lk5);
                lerr = fmaxf(lerr, fabsf(x5 - x4));
                lsp = fmaxf(lsp, fabsf(x5 - xv));
                x5out[idx] = x5;
            }
        }
    }

    if constexpr (S == 6) {
#pragma unroll
        for (int off = 32; off > 0; off >>= 1) {
            lerr = fmaxf(lerr, __shfl_down(lerr, off));
            lsp = fmaxf(lsp, __shfl_down(lsp, off));
        }
        if (li == 0) {
            serr[wid] = lerr;
            ssp[wid] = lsp;
        }
        __syncthreads();
        if (tid == 0) {
            float e = serr[0], s = ssp[0];
#pragma unroll
            for (int w = 1; w < 8; ++w) {
                e = fmaxf(e, serr[w]);
                s = fmaxf(s, ssp[w]);
            }
            atomicMax((unsigned int*)&scal[SC_ERR], __float_as_uint(e));
            atomicMax((unsigned int*)&scal[SC_SP], __float_as_uint(s));
        }
    }
}

// ---------------- fused scalar update + commit ----------------

__global__ void commit_fused(float* __restrict__ x, const float* __restrict__ x5,
                             _Float16* __restrict__ Axh, _Float16* __restrict__ Axl,
                             const float* __restrict__ scal_rd, float* __restrict__ scal_wr) {
    float dt = scal_rd[SC_DT];
    float err = scal_rd[SC_ERR];
    float sp = scal_rd[SC_SP];
    unsigned int done = ((const unsigned int*)scal_rd)[SC_DONE];
    bool accept = err < TOLF;
    bool step = accept && (done == 0u);
    float speed = sp / dt;
    unsigned int done_new = (done || (step && speed < SPEED_TOLF)) ? 1u : 0u;
    float scale = 0.9f * powf(TOLF / (err + 1e-12f), 0.2f);
    scale = fminf(fmaxf(scale, 0.1f), 4.0f);
    float dtn = fmaxf(dt * scale, MIN_DTF);
    if (blockIdx.x == 0 && threadIdx.x == 0) {
        scal_wr[SC_DT] = done ? dt : dtn;
        ((unsigned int*)scal_wr)[SC_DONE] = done_new;
        scal_wr[SC_ERR] = 0.0f;
        scal_wr[SC_SP] = 0.0f;
    }
    if (!step) return;  // x unchanged; Ax split still valid
    int tid = blockIdx.x * blockDim.x + threadIdx.x;
    float4* X = (float4*)x;
    const float4* X5 = (const float4*)x5;
    for (int i = tid; i < NV4; i += gridDim.x * blockDim.x) {
        float4 v = X5[i];
        X[i] = v;
        half4v h, l;
        float vv[4] = {v.x, v.y, v.z, v.w};
#pragma unroll
        for (int q = 0; q < 4; ++q) {
            float y = reflect_f(vv[q]);
            _Float16 hh, ll;
            split_f16(y, hh, ll);
            h[q] = hh;
            l[q] = ll;
        }
        *(half4v*)&Axh[(size_t)i * 4] = h;
        *(half4v*)&Axl[(size_t)i * 4] = l;
    }
}

// ---------------- launch ----------------

extern "C" void kernel_launch(void* const* d_in, const int* in_sizes, int n_in, void* d_out,
                              int out_size, void* d_ws, size_t ws_size, hipStream_t stream) {
    const float* x0 = (const float*)d_in[0];
    const float* W = (const float*)d_in[1];
    const float* bias = (const float*)d_in[2];
    float* x = (float*)d_out;

    float* ws = (float*)d_ws;
    float* k1 = ws + 0 * (size_t)NELEM;
    float* k2 = ws + 1 * (size_t)NELEM;
    float* k3 = ws + 2 * (size_t)NELEM;
    float* k4 = ws + 3 * (size_t)NELEM;
    float* k5 = ws + 4 * (size_t)NELEM;
    float* x5 = ws + 5 * (size_t)NELEM;
    float* scal = ws + 6 * (size_t)NELEM;  // 2 parity slots x 8 floats
    _Float16* hb = (_Float16*)(ws + 6 * (size_t)NELEM + 64);
    _Float16* Axh = hb + 0 * (size_t)NELEM;
    _Float16* Axl = hb + 1 * (size_t)NELEM;
    _Float16* P0h = hb + 2 * (size_t)NELEM;
    _Float16* P0l = hb + 3 * (size_t)NELEM;
    _Float16* P1h = hb + 4 * (size_t)NELEM;
    _Float16* P1l = hb + 5 * (size_t)NELEM;
    _Float16* Whf = hb + 6 * (size_t)NELEM;
    _Float16* Wlf = Whf + (size_t)DDIM * DDIM;

    wconv_kernel<<<2048, 256, 0, stream>>>(W, Whf, Wlf);
    init_kernel<<<1024, 256, 0, stream>>>(x0, x, Axh, Axl, scal);

    for (int it = 0; it < 32; ++it) {
        float* sp = scal + (it & 1) * 8;
        float* sn = scal + ((it + 1) & 1) * 8;
        stage_kernel<1><<<256, 512, 0, stream>>>(Axh, Axl, P0h, P0l, Whf, Wlf, bias, x, k1, k2,
                                                 k3, k4, k5, k1, x5, sp);
        stage_kernel<2><<<256, 512, 0, stream>>>(P0h, P0l, P1h, P1l, Whf, Wlf, bias, x, k1, k2,
                                                 k3, k4, k5, k2, x5, sp);
        stage_kernel<3><<<256, 512, 0, stream>>>(P1h, P1l, P0h, P0l, Whf, Wlf, bias, x, k1, k2,
                                                 k3, k4, k5, k3, x5, sp);
        stage_kernel<4><<<256, 512, 0, stream>>>(P0h, P0l, P1h, P1l, Whf, Wlf, bias, x, k1, k2,
                                                 k3, k4, k5, k4, x5, sp);
        stage_kernel<5><<<256, 512, 0, stream>>>(P1h, P1l, P0h, P0l, Whf, Wlf, bias, x, k1, k2,
                                                 k3, k4, k5, k5, x5, sp);
        stage_kernel<6><<<256, 512, 0, stream>>>(P0h, P0l, P1h, P1l, Whf, Wlf, bias, x, k1, k2,
                                                 k3, k4, k5, k1, x5, sp);
        commit_fused<<<1024, 256, 0, stream>>>(x, x5, Axh, Axl, sp, sn);
    }
}